// Round 19
// baseline (693.245 us; speedup 1.0000x reference)
//
#include <hip/hip_runtime.h>
#include <cstdint>
#include <cstddef>

typedef short bf16x8 __attribute__((ext_vector_type(8)));
typedef float f32x4 __attribute__((ext_vector_type(4)));

#define HH 48
#define WW 64
#define HWSZ 3072
#define SCALE_Q 0.08838834764831845f

__device__ __forceinline__ float b2f(unsigned short u) {
    union { unsigned int i; float f; } c; c.i = ((unsigned int)u) << 16; return c.f;
}
__device__ __forceinline__ unsigned short f2b(float f) {
    union { float f; unsigned int i; } c; c.f = f;
    unsigned int r = (c.i + 0x7fffu + ((c.i >> 16) & 1u)) >> 16;
    return (unsigned short)r;
}

// async global->LDS, 16B per lane; LDS dest is wave-uniform base (HW adds lane*16)
__device__ __forceinline__ void dma16(const unsigned short* g, unsigned short* l) {
    __builtin_amdgcn_global_load_lds((const __attribute__((address_space(1))) unsigned int*)g,
                                     (__attribute__((address_space(3))) unsigned int*)l,
                                     16, 0, 0);
}

// ---------------- K0a: fmap (fb, c, pos) f32 -> Xb (fb, pos, c) bf16 ----------------
__global__ __launch_bounds__(256) void k_transpose(const float* __restrict__ f0,
                                                   const float* __restrict__ f1,
                                                   unsigned short* __restrict__ Xb) {
    __shared__ float t[32][33];
    int fb = blockIdx.z; int f = fb >> 1, bb = fb & 1;
    const float* src = f ? f1 : f0;
    int pT = blockIdx.x * 32, cT = blockIdx.y * 32;
    int tx = threadIdx.x, ty = threadIdx.y;
#pragma unroll
    for (int i = 0; i < 4; ++i) {
        int c = cT + ty + i * 8, pos = pT + tx;
        t[ty + i * 8][tx] = src[(size_t)(bb * 128 + c) * HWSZ + pos];
    }
    __syncthreads();
#pragma unroll
    for (int i = 0; i < 4; ++i) {
        int pos = pT + ty + i * 8, c = cT + tx;
        Xb[(size_t)(fb * HWSZ + pos) * 128 + c] = f2b(t[tx][ty + i * 8]);
    }
}

// ---------------- K0b: weights -> bf16 ----------------
__global__ __launch_bounds__(256) void k_weights(const float* __restrict__ Wqk,
                                                 const float* __restrict__ Wv,
                                                 const float* __restrict__ Wp,
                                                 unsigned short* __restrict__ Wcat,
                                                 unsigned short* __restrict__ Wpb) {
    int idx = blockIdx.x * 256 + threadIdx.x;
    if (idx < 131072) {
        int o = idx >> 7, c = idx & 127;
        float v = (o < 512) ? Wqk[o * 128 + c] * SCALE_Q : Wv[(o - 512) * 128 + c];
        Wcat[idx] = f2b(v);
    } else {
        int j = idx - 131072;
        Wpb[j] = f2b(Wp[j]);
    }
}

// ---------------- K1: q/v projections; V stored as [fbn][u][d][64v] tiles ----------------
__global__ __launch_bounds__(256) void k_qv(const unsigned short* __restrict__ Xb,
                                            const unsigned short* __restrict__ Wcat,
                                            unsigned short* __restrict__ Qx,
                                            unsigned short* __restrict__ Vt) {
    __shared__ unsigned short Asub[64 * 136];
    __shared__ unsigned short Bsub[128 * 136];
    int mt = blockIdx.x, nt = blockIdx.y, fb = blockIdx.z;
    int tid = threadIdx.x;
    const unsigned short* asrc = Xb + (size_t)(fb * HWSZ + mt * 64) * 128;
    const unsigned short* bsrc = Wcat + (size_t)nt * 128 * 128;
    for (int ch = tid; ch < 1024; ch += 256) {
        int row = ch >> 4, seg = ch & 15;
        *(bf16x8*)&Asub[row * 136 + seg * 8] = *(const bf16x8*)(asrc + ch * 8);
    }
    for (int ch = tid; ch < 2048; ch += 256) {
        int row = ch >> 4, seg = ch & 15;
        *(bf16x8*)&Bsub[row * 136 + seg * 8] = *(const bf16x8*)(bsrc + ch * 8);
    }
    __syncthreads();
    int l = tid & 63, w = tid >> 6;
    int wm = w >> 1, wn = w & 1;
    int lr = l & 15, lk8 = (l >> 4) * 8;
    f32x4 acc[2][4] = {};
#pragma unroll
    for (int kt = 0; kt < 4; ++kt) {
        bf16x8 a[2], b[4];
#pragma unroll
        for (int m = 0; m < 2; ++m)
            a[m] = *(const bf16x8*)&Asub[(wm * 32 + m * 16 + lr) * 136 + kt * 32 + lk8];
#pragma unroll
        for (int n = 0; n < 4; ++n)
            b[n] = *(const bf16x8*)&Bsub[(wn * 64 + n * 16 + lr) * 136 + kt * 32 + lk8];
#pragma unroll
        for (int m = 0; m < 2; ++m)
#pragma unroll
            for (int n = 0; n < 4; ++n)
                acc[m][n] = __builtin_amdgcn_mfma_f32_16x16x32_bf16(a[m], b[n], acc[m][n], 0, 0, 0);
    }
    int f = fb >> 1, bb = fb & 1;
#pragma unroll
    for (int m = 0; m < 2; ++m)
#pragma unroll
        for (int n = 0; n < 4; ++n) {
            int o = nt * 128 + wn * 64 + n * 16 + lr;
            int pos0 = mt * 64 + wm * 32 + m * 16 + (l >> 4) * 4;
            if (o < 512) {
                int nh = o >> 7, d = o & 127;
#pragma unroll
                for (int r = 0; r < 4; ++r) {
                    int pos = pos0 + r, x = pos >> 6, y = pos & 63;
                    Qx[(size_t)((f * 48 + x) * 512 + (bb * 4 + nh) * 64 + y) * 128 + d] = f2b(acc[m][n][r]);
                }
            } else {
                int oo = o - 512, nh = oo >> 7, d = oo & 127;
                int u = pos0 >> 6, v = pos0 & 63;
                uint2 val;
                val.x = (unsigned int)f2b(acc[m][n][0]) | ((unsigned int)f2b(acc[m][n][1]) << 16);
                val.y = (unsigned int)f2b(acc[m][n][2]) | ((unsigned int)f2b(acc[m][n][3]) << 16);
                *(uint2*)&Vt[(((size_t)(fb * 4 + nh) * 48 + u) * 128 + d) * 64 + v] = val;
            }
        }
}

// ---------------- K2a: ph softmax over u (mt split over z) ----------------
__global__ __launch_bounds__(256) void k_ph(const unsigned short* __restrict__ Qx,
                                            const float* __restrict__ rel_h,
                                            unsigned short* __restrict__ PH) {
    __shared__ float sm[4][16][52];
    int x = blockIdx.x, f = blockIdx.y, mtz = blockIdx.z;
    int tid = threadIdx.x, l = tid & 63, w = tid >> 6;
    int lr = l & 15, lk8 = (l >> 4) * 8;
    bf16x8 bh[3][4];
#pragma unroll
    for (int ut = 0; ut < 3; ++ut) {
        int u = ut * 16 + lr, rr = x - u + 99;
#pragma unroll
        for (int kt = 0; kt < 4; ++kt) {
            const float* s = rel_h + rr * 128 + kt * 32 + lk8;
            float4 a0 = *(const float4*)s, a1 = *(const float4*)(s + 4);
            bf16x8 pk;
            pk[0] = (short)f2b(a0.x); pk[1] = (short)f2b(a0.y); pk[2] = (short)f2b(a0.z); pk[3] = (short)f2b(a0.w);
            pk[4] = (short)f2b(a1.x); pk[5] = (short)f2b(a1.y); pk[6] = (short)f2b(a1.z); pk[7] = (short)f2b(a1.w);
            bh[ut][kt] = pk;
        }
    }
    const unsigned short* qbase = Qx + (size_t)(f * 48 + x) * 512 * 128;
    unsigned short* phbase = PH + (size_t)(f * 48 + x) * 512 * 48;
    for (int mt = mtz * 2; mt < mtz * 2 + 2; ++mt) {
        int rg = w * 128 + mt * 16 + lr;
        const unsigned short* qrow = qbase + (size_t)rg * 128;
        bf16x8 a[4];
#pragma unroll
        for (int kt = 0; kt < 4; ++kt) a[kt] = *(const bf16x8*)(qrow + kt * 32 + lk8);
        f32x4 acc[3] = {};
#pragma unroll
        for (int kt = 0; kt < 4; ++kt)
#pragma unroll
            for (int ut = 0; ut < 3; ++ut)
                acc[ut] = __builtin_amdgcn_mfma_f32_16x16x32_bf16(a[kt], bh[ut][kt], acc[ut], 0, 0, 0);
        __syncthreads();
#pragma unroll
        for (int ut = 0; ut < 3; ++ut)
#pragma unroll
            for (int r = 0; r < 4; ++r)
                sm[w][(l >> 4) * 4 + r][ut * 16 + lr] = acc[ut][r];
        __syncthreads();
        int part = l >> 4;
        float vb[12];
        float mx = -1e30f;
#pragma unroll
        for (int j = 0; j < 12; ++j) { vb[j] = sm[w][lr][part * 12 + j]; mx = fmaxf(mx, vb[j]); }
        mx = fmaxf(mx, __shfl_xor(mx, 16, 64));
        mx = fmaxf(mx, __shfl_xor(mx, 32, 64));
        float ssum = 0.f;
#pragma unroll
        for (int j = 0; j < 12; ++j) { vb[j] = __expf(vb[j] - mx); ssum += vb[j]; }
        ssum += __shfl_xor(ssum, 16, 64);
        ssum += __shfl_xor(ssum, 32, 64);
        float inv = 1.0f / ssum;
        unsigned short* dst = phbase + (size_t)(w * 128 + mt * 16 + lr) * 48 + part * 12;
#pragma unroll
        for (int j = 0; j < 12; ++j) dst[j] = f2b(vb[j] * inv);
    }
}

// ---------------- K2b: pw softmax over v (mt split over z) ----------------
__global__ __launch_bounds__(256) void k_pw(const unsigned short* __restrict__ Qx,
                                            const float* __restrict__ rel_w,
                                            unsigned short* __restrict__ PW) {
    __shared__ float sm[4][16][68];
    int y = blockIdx.x, f = blockIdx.y, mtz = blockIdx.z;
    int tid = threadIdx.x, l = tid & 63, w = tid >> 6;
    int lr = l & 15, lk8 = (l >> 4) * 8;
    bf16x8 bw[4][4];
#pragma unroll
    for (int vt = 0; vt < 4; ++vt) {
        int v = vt * 16 + lr, rr = y - v + 99;
#pragma unroll
        for (int kt = 0; kt < 4; ++kt) {
            const float* s = rel_w + rr * 128 + kt * 32 + lk8;
            float4 a0 = *(const float4*)s, a1 = *(const float4*)(s + 4);
            bf16x8 pk;
            pk[0] = (short)f2b(a0.x); pk[1] = (short)f2b(a0.y); pk[2] = (short)f2b(a0.z); pk[3] = (short)f2b(a0.w);
            pk[4] = (short)f2b(a1.x); pk[5] = (short)f2b(a1.y); pk[6] = (short)f2b(a1.z); pk[7] = (short)f2b(a1.w);
            bw[vt][kt] = pk;
        }
    }
    for (int mt = mtz * 2; mt < mtz * 2 + 2; ++mt) {
        int rg = w * 96 + mt * 16 + lr;
        int bn = rg / 48, xx = rg - bn * 48;
        const unsigned short* qrow = Qx + (size_t)((f * 48 + xx) * 512 + bn * 64 + y) * 128;
        bf16x8 a[4];
#pragma unroll
        for (int kt = 0; kt < 4; ++kt) a[kt] = *(const bf16x8*)(qrow + kt * 32 + lk8);
        f32x4 acc[4] = {};
#pragma unroll
        for (int kt = 0; kt < 4; ++kt)
#pragma unroll
            for (int vt = 0; vt < 4; ++vt)
                acc[vt] = __builtin_amdgcn_mfma_f32_16x16x32_bf16(a[kt], bw[vt][kt], acc[vt], 0, 0, 0);
        __syncthreads();
#pragma unroll
        for (int vt = 0; vt < 4; ++vt)
#pragma unroll
            for (int r = 0; r < 4; ++r)
                sm[w][(l >> 4) * 4 + r][vt * 16 + lr] = acc[vt][r];
        __syncthreads();
        int part = l >> 4;
        float vb[16];
        float mx = -1e30f;
#pragma unroll
        for (int j = 0; j < 16; ++j) { vb[j] = sm[w][lr][part * 16 + j]; mx = fmaxf(mx, vb[j]); }
        mx = fmaxf(mx, __shfl_xor(mx, 16, 64));
        mx = fmaxf(mx, __shfl_xor(mx, 32, 64));
        float ssum = 0.f;
#pragma unroll
        for (int j = 0; j < 16; ++j) { vb[j] = __expf(vb[j] - mx); ssum += vb[j]; }
        ssum += __shfl_xor(ssum, 16, 64);
        ssum += __shfl_xor(ssum, 32, 64);
        float inv = 1.0f / ssum;
        unsigned short* dst = PW + (size_t)((f * 64 + y) * 384 + rg) * 64 + part * 16;
#pragma unroll
        for (int j = 0; j < 16; ++j) dst[j] = f2b(vb[j] * inv);
    }
}

// ---------------- K3 v14: split-u (2 halves), lockstep DMA phases, launch_bounds(256,3) ----------------
// Grid 1536 = 16 fbn x (24 t x 2 dh x 2 uh) -> 6 blocks/CU (TLP). Register plan as R13 (no spill).
// Per u: DMA u+1 in flight, 16 MFMA, drain vmcnt(0)+barrier (FETCH-safe self-pacing).
__global__ __launch_bounds__(256, 3) void k_attn(const unsigned short* __restrict__ PH,
                                                 const unsigned short* __restrict__ PW,
                                                 const unsigned short* __restrict__ Vt,
                                                 unsigned short* __restrict__ AO0,
                                                 unsigned short* __restrict__ AO1) {
    __shared__ unsigned short phl[24 * 128];        // [u-local][(q&15)*8 + (q>>4)] bf16 (6 KB)
    __shared__ unsigned short vbuf[2][4096];        // double-buffered u-tile half, swz (16 KB)
    int bid = blockIdx.x;
    int r16 = bid & 15;
    int rest = bid >> 4;                            // 0..95
    int t = rest >> 2, dh = (rest >> 1) & 1, uh = rest & 1;
    int fbn = (r16 & 7) * 2 + (r16 >> 3);           // XCD-local V reuse
    int f = fbn >> 3, bidx = (fbn >> 2) & 1, nh = fbn & 3;
    int fb = f * 2 + bidx, bn = bidx * 4 + nh;
    int ubase = uh * 24;
    int tid = threadIdx.x;
    int l = tid & 63, wd = tid >> 6;
    int lr = l & 15, lg = l >> 4, lk8 = lg * 8;

    // DMA source offsets (shorts, half-tile local, inverse-swizzled per lane)
    const unsigned short* vhalf = Vt + (size_t)(fb * 4 + nh) * 48 * 8192 + dh * 4096;
    int r0 = wd * 16 + (l >> 3), s0 = l & 7;
    int r1 = r0 + 8;
    int g0 = r0 * 64 + ((s0 ^ (r0 & 7)) * 8);
    int g1 = r1 * 64 + ((s0 ^ (r1 & 7)) * 8);

#define DMA_U(BUF, U)                                                           \
    {                                                                           \
        const unsigned short* gt = vhalf + (size_t)(U) * 8192;                  \
        dma16(gt + g0, &vbuf[BUF][wd * 1024]);                                  \
        dma16(gt + g1, &vbuf[BUF][wd * 1024 + 512]);                            \
    }

    DMA_U(0, ubase);   // tile 0 in flight under the staging below

    // stage ph slice: packed layout [u-local][(q&15)*8 + (q>>4)]
    for (int i = tid; i < 1536; i += 256) {
        int up2l = i >> 7, q = i & 127;
        int up2 = uh * 12 + up2l;
        int xy = t * 128 + q, x = xy >> 6, y = xy & 63;
        unsigned int wv = *(const unsigned int*)(PH + ((size_t)(f * 48 + x) * 512 + bn * 64 + y) * 48 + up2 * 2);
        int qoff = (q & 15) * 8 + (q >> 4);
        phl[(up2l * 2) * 128 + qoff]     = (unsigned short)(wv & 0xffffu);
        phl[(up2l * 2 + 1) * 128 + qoff] = (unsigned short)(wv >> 16);
    }
    // pw B-fragments: 8 n-frags x 2 k-halves in registers
    bf16x8 b[8][2];
#pragma unroll
    for (int n = 0; n < 8; ++n) {
        int xy = t * 128 + n * 16 + lr;
        int x = xy >> 6, y = xy & 63;
        const unsigned short* pwr = PW + ((size_t)(f * 64 + y) * 384 + bn * 48 + x) * 64;
        b[n][0] = *(const bf16x8*)(pwr + lk8);
        b[n][1] = *(const bf16x8*)(pwr + 32 + lk8);
    }
    asm volatile("s_waitcnt vmcnt(0)" ::: "memory");
    __syncthreads();

    int arow = wd * 16 + lr;
    int ao0 = arow * 64 + ((lg ^ (arow & 7)) * 8);
    int ao1 = arow * 64 + (((4 + lg) ^ (arow & 7)) * 8);
    const unsigned short* phrow = &phl[lr * 8];
    f32x4 acc[8] = {};
    const f32x4 zero4 = {0.f, 0.f, 0.f, 0.f};

    int buf = 0;
    for (int i = 0; i < 24; ++i) {
        if (i + 1 < 24) DMA_U(buf ^ 1, ubase + i + 1);   // in flight across this phase's compute
        bf16x8 av0 = *(const bf16x8*)&vbuf[buf][ao0];
        bf16x8 av1 = *(const bf16x8*)&vbuf[buf][ao1];
        bf16x8 phv = *(const bf16x8*)(phrow + i * 128);
        __builtin_amdgcn_s_setprio(1);
#pragma unroll
        for (int n = 0; n < 8; ++n) {
            f32x4 Y = __builtin_amdgcn_mfma_f32_16x16x32_bf16(av0, b[n][0], zero4, 0, 0, 0);
            Y = __builtin_amdgcn_mfma_f32_16x16x32_bf16(av1, b[n][1], Y, 0, 0, 0);
            acc[n] += b2f((unsigned short)phv[n]) * Y;
        }
        __builtin_amdgcn_s_setprio(0);
        asm volatile("s_waitcnt vmcnt(0)" ::: "memory");   // drain: self-pacing (FETCH-safe)
        __syncthreads();
        buf ^= 1;
    }
#undef DMA_U

    // store partial: lane col q = t*128 + n*16 + lr; rows d = dh*64 + wd*16 + lg*4 (+r)
    unsigned short* AOx = uh ? AO1 : AO0;
    unsigned short* aobase = AOx + (size_t)fb * HWSZ * 512 + nh * 128 + dh * 64 + wd * 16 + lg * 4;
#pragma unroll
    for (int n = 0; n < 8; ++n) {
        int q = t * 128 + n * 16 + lr;
        uint2 val;
        val.x = (unsigned int)f2b(acc[n][0]) | ((unsigned int)f2b(acc[n][1]) << 16);
        val.y = (unsigned int)f2b(acc[n][2]) | ((unsigned int)f2b(acc[n][3]) << 16);
        *(uint2*)(aobase + (size_t)q * 512) = val;
    }
}

// ---------------- K4: out = fmap + gamma * ((AO0+AO1) @ Wp^T), 32-row tiles ----------------
__global__ __launch_bounds__(256) void k_proj(const unsigned short* __restrict__ AO0,
                                              const unsigned short* __restrict__ AO1,
                                              const unsigned short* __restrict__ Wpb,
                                              const float* __restrict__ f0,
                                              const float* __restrict__ f1,
                                              const float* __restrict__ gamma,
                                              float* __restrict__ out) {
    __shared__ unsigned short Asub[32 * 136];
    __shared__ unsigned short Bsub[128 * 136];
    int t = blockIdx.x, fb = blockIdx.y;
    int f = fb >> 1, bb = fb & 1;
    int tid = threadIdx.x;
    int l = tid & 63, w = tid >> 6;
    int wm = w >> 1, wn = w & 1;
    int lr = l & 15, lk8 = (l >> 4) * 8;
    f32x4 acc[4] = {};
    for (int ks = 0; ks < 4; ++ks) {
        if (ks) __syncthreads();
        for (int ch = tid; ch < 512; ch += 256) {
            int row = ch >> 4, seg = ch & 15;
            size_t off = (size_t)(fb * HWSZ + t * 32 + row) * 512 + ks * 128 + seg * 8;
            bf16x8 a0 = *(const bf16x8*)(AO0 + off);
            bf16x8 a1 = *(const bf16x8*)(AO1 + off);
            bf16x8 sv;
#pragma unroll
            for (int j = 0; j < 8; ++j)
                sv[j] = (short)f2b(b2f((unsigned short)a0[j]) + b2f((unsigned short)a1[j]));
            *(bf16x8*)&Asub[row * 136 + seg * 8] = sv;
        }
        for (int ch = tid; ch < 2048; ch += 256) {
            int row = ch >> 4, seg = ch & 15;
            *(bf16x8*)&Bsub[row * 136 + seg * 8] =
                *(const bf16x8*)(Wpb + (size_t)row * 512 + ks * 128 + seg * 8);
        }
        __syncthreads();
#pragma unroll
        for (int kt = 0; kt < 4; ++kt) {
            bf16x8 a, b[4];
            a = *(const bf16x8*)&Asub[(wm * 16 + lr) * 136 + kt * 32 + lk8];
#pragma unroll
            for (int n = 0; n < 4; ++n)
                b[n] = *(const bf16x8*)&Bsub[(wn * 64 + n * 16 + lr) * 136 + kt * 32 + lk8];
#pragma unroll
            for (int n = 0; n < 4; ++n)
                acc[n] = __builtin_amdgcn_mfma_f32_16x16x32_bf16(a, b[n], acc[n], 0, 0, 0);
        }
    }
    const float* fmapf = f ? f1 : f0;
    float g = gamma[0];
#pragma unroll
    for (int n = 0; n < 4; ++n) {
        int c = wn * 64 + n * 16 + lr;
        int pos0 = t * 32 + wm * 16 + (l >> 4) * 4;
        size_t addr = (size_t)(bb * 128 + c) * HWSZ + pos0;
        float4 fv = *(const float4*)(fmapf + addr);
        float4 ov;
        ov.x = fv.x + g * acc[n][0];
        ov.y = fv.y + g * acc[n][1];
        ov.z = fv.z + g * acc[n][2];
        ov.w = fv.w + g * acc[n][3];
        *(float4*)(out + (size_t)f * 786432 + addr) = ov;
    }
}

extern "C" void kernel_launch(void* const* d_in, const int* in_sizes, int n_in,
                              void* d_out, int out_size, void* d_ws, size_t ws_size,
                              hipStream_t stream) {
    (void)in_sizes; (void)n_in; (void)out_size; (void)ws_size;
    const float* fmap1 = (const float*)d_in[0];
    const float* fmap2 = (const float*)d_in[1];
    const float* Wqk   = (const float*)d_in[2];
    const float* Wv    = (const float*)d_in[3];
    const float* rel_h = (const float*)d_in[4];
    const float* rel_w = (const float*)d_in[5];
    const float* Wp    = (const float*)d_in[6];
    const float* gamma = (const float*)d_in[7];
    float* out = (float*)d_out;
    char* ws = (char*)d_ws;

    unsigned short* Xb   = (unsigned short*)(ws + 0);
    unsigned short* Wcat = (unsigned short*)(ws + 3145728);
    unsigned short* Wpb  = (unsigned short*)(ws + 3407872);
    unsigned short* Qx   = (unsigned short*)(ws + 3538944);
    unsigned short* AO0  = Qx;                               // alias: Qx dead after k_ph/k_pw
    unsigned short* Vt   = (unsigned short*)(ws + 16121856);
    unsigned short* PH   = (unsigned short*)(ws + 28704768);
    unsigned short* PW   = (unsigned short*)(ws + 33423360);
    unsigned short* AO1  = (unsigned short*)(ws + 39714816); // 12,582,912 (end 52,297,728)

    k_transpose<<<dim3(96, 4, 4), dim3(32, 8), 0, stream>>>(fmap1, fmap2, Xb);
    k_weights<<<dim3(768), dim3(256), 0, stream>>>(Wqk, Wv, Wp, Wcat, Wpb);
    k_qv<<<dim3(48, 8, 4), dim3(256), 0, stream>>>(Xb, Wcat, Qx, Vt);
    k_ph<<<dim3(48, 2, 4), dim3(256), 0, stream>>>(Qx, rel_h, PH);
    k_pw<<<dim3(64, 2, 3), dim3(256), 0, stream>>>(Qx, rel_w, PW);
    k_attn<<<dim3(1536), dim3(256), 0, stream>>>(PH, PW, Vt, AO0, AO1);
    k_proj<<<dim3(96, 4), dim3(256), 0, stream>>>(AO0, AO1, Wpb, fmap1, fmap2, gamma, out);
}

// Round 20
// 111.337 us; speedup vs baseline: 6.2265x; 6.2265x over previous
//
#include <hip/hip_runtime.h>
#include <cstdint>
#include <cstddef>

typedef short bf16x8 __attribute__((ext_vector_type(8)));
typedef float f32x4 __attribute__((ext_vector_type(4)));

#define HH 48
#define WW 64
#define HWSZ 3072
#define SCALE_Q 0.08838834764831845f

__device__ __forceinline__ float b2f(unsigned short u) {
    union { unsigned int i; float f; } c; c.i = ((unsigned int)u) << 16; return c.f;
}
__device__ __forceinline__ unsigned short f2b(float f) {
    union { float f; unsigned int i; } c; c.f = f;
    unsigned int r = (c.i + 0x7fffu + ((c.i >> 16) & 1u)) >> 16;
    return (unsigned short)r;
}

// ---------------- K0a: fmap (fb, c, pos) f32 -> Xb (fb, pos, c) bf16 ----------------
__global__ __launch_bounds__(256) void k_transpose(const float* __restrict__ f0,
                                                   const float* __restrict__ f1,
                                                   unsigned short* __restrict__ Xb) {
    __shared__ float t[32][33];
    int fb = blockIdx.z; int f = fb >> 1, bb = fb & 1;
    const float* src = f ? f1 : f0;
    int pT = blockIdx.x * 32, cT = blockIdx.y * 32;
    int tx = threadIdx.x, ty = threadIdx.y;
#pragma unroll
    for (int i = 0; i < 4; ++i) {
        int c = cT + ty + i * 8, pos = pT + tx;
        t[ty + i * 8][tx] = src[(size_t)(bb * 128 + c) * HWSZ + pos];
    }
    __syncthreads();
#pragma unroll
    for (int i = 0; i < 4; ++i) {
        int pos = pT + ty + i * 8, c = cT + tx;
        Xb[(size_t)(fb * HWSZ + pos) * 128 + c] = f2b(t[tx][ty + i * 8]);
    }
}

// ---------------- K0b: weights -> bf16 ----------------
__global__ __launch_bounds__(256) void k_weights(const float* __restrict__ Wqk,
                                                 const float* __restrict__ Wv,
                                                 const float* __restrict__ Wp,
                                                 unsigned short* __restrict__ Wcat,
                                                 unsigned short* __restrict__ Wpb) {
    int idx = blockIdx.x * 256 + threadIdx.x;
    if (idx < 131072) {
        int o = idx >> 7, c = idx & 127;
        float v = (o < 512) ? Wqk[o * 128 + c] * SCALE_Q : Wv[(o - 512) * 128 + c];
        Wcat[idx] = f2b(v);
    } else {
        int j = idx - 131072;
        Wpb[j] = f2b(Wp[j]);
    }
}

// ---------------- K1: q/v projections; V stored as [fbn][d][key] (R9 layout) ----------------
__global__ __launch_bounds__(256) void k_qv(const unsigned short* __restrict__ Xb,
                                            const unsigned short* __restrict__ Wcat,
                                            unsigned short* __restrict__ Qx,
                                            unsigned short* __restrict__ Vt) {
    __shared__ unsigned short Asub[64 * 136];
    __shared__ unsigned short Bsub[128 * 136];
    int mt = blockIdx.x, nt = blockIdx.y, fb = blockIdx.z;
    int tid = threadIdx.x;
    const unsigned short* asrc = Xb + (size_t)(fb * HWSZ + mt * 64) * 128;
    const unsigned short* bsrc = Wcat + (size_t)nt * 128 * 128;
    for (int ch = tid; ch < 1024; ch += 256) {
        int row = ch >> 4, seg = ch & 15;
        *(bf16x8*)&Asub[row * 136 + seg * 8] = *(const bf16x8*)(asrc + ch * 8);
    }
    for (int ch = tid; ch < 2048; ch += 256) {
        int row = ch >> 4, seg = ch & 15;
        *(bf16x8*)&Bsub[row * 136 + seg * 8] = *(const bf16x8*)(bsrc + ch * 8);
    }
    __syncthreads();
    int l = tid & 63, w = tid >> 6;
    int wm = w >> 1, wn = w & 1;
    int lr = l & 15, lk8 = (l >> 4) * 8;
    f32x4 acc[2][4] = {};
#pragma unroll
    for (int kt = 0; kt < 4; ++kt) {
        bf16x8 a[2], b[4];
#pragma unroll
        for (int m = 0; m < 2; ++m)
            a[m] = *(const bf16x8*)&Asub[(wm * 32 + m * 16 + lr) * 136 + kt * 32 + lk8];
#pragma unroll
        for (int n = 0; n < 4; ++n)
            b[n] = *(const bf16x8*)&Bsub[(wn * 64 + n * 16 + lr) * 136 + kt * 32 + lk8];
#pragma unroll
        for (int m = 0; m < 2; ++m)
#pragma unroll
            for (int n = 0; n < 4; ++n)
                acc[m][n] = __builtin_amdgcn_mfma_f32_16x16x32_bf16(a[m], b[n], acc[m][n], 0, 0, 0);
    }
    int f = fb >> 1, bb = fb & 1;
#pragma unroll
    for (int m = 0; m < 2; ++m)
#pragma unroll
        for (int n = 0; n < 4; ++n) {
            int o = nt * 128 + wn * 64 + n * 16 + lr;
            int pos0 = mt * 64 + wm * 32 + m * 16 + (l >> 4) * 4;
            if (o < 512) {
                int nh = o >> 7, d = o & 127;
#pragma unroll
                for (int r = 0; r < 4; ++r) {
                    int pos = pos0 + r, x = pos >> 6, y = pos & 63;
                    Qx[(size_t)((f * 48 + x) * 512 + (bb * 4 + nh) * 64 + y) * 128 + d] = f2b(acc[m][n][r]);
                }
            } else {
                int oo = o - 512, nh = oo >> 7, d = oo & 127;
                uint2 val;
                val.x = (unsigned int)f2b(acc[m][n][0]) | ((unsigned int)f2b(acc[m][n][1]) << 16);
                val.y = (unsigned int)f2b(acc[m][n][2]) | ((unsigned int)f2b(acc[m][n][3]) << 16);
                *(uint2*)&Vt[(size_t)((fb * 4 + nh) * 128 + d) * HWSZ + pos0] = val;
            }
        }
}

// ---------------- K2a: ph softmax over u (mt split over z) ----------------
__global__ __launch_bounds__(256) void k_ph(const unsigned short* __restrict__ Qx,
                                            const float* __restrict__ rel_h,
                                            unsigned short* __restrict__ PH) {
    __shared__ float sm[4][16][52];
    int x = blockIdx.x, f = blockIdx.y, mtz = blockIdx.z;
    int tid = threadIdx.x, l = tid & 63, w = tid >> 6;
    int lr = l & 15, lk8 = (l >> 4) * 8;
    bf16x8 bh[3][4];
#pragma unroll
    for (int ut = 0; ut < 3; ++ut) {
        int u = ut * 16 + lr, rr = x - u + 99;
#pragma unroll
        for (int kt = 0; kt < 4; ++kt) {
            const float* s = rel_h + rr * 128 + kt * 32 + lk8;
            float4 a0 = *(const float4*)s, a1 = *(const float4*)(s + 4);
            bf16x8 pk;
            pk[0] = (short)f2b(a0.x); pk[1] = (short)f2b(a0.y); pk[2] = (short)f2b(a0.z); pk[3] = (short)f2b(a0.w);
            pk[4] = (short)f2b(a1.x); pk[5] = (short)f2b(a1.y); pk[6] = (short)f2b(a1.z); pk[7] = (short)f2b(a1.w);
            bh[ut][kt] = pk;
        }
    }
    const unsigned short* qbase = Qx + (size_t)(f * 48 + x) * 512 * 128;
    unsigned short* phbase = PH + (size_t)(f * 48 + x) * 512 * 48;
    for (int mt = mtz * 2; mt < mtz * 2 + 2; ++mt) {
        int rg = w * 128 + mt * 16 + lr;
        const unsigned short* qrow = qbase + (size_t)rg * 128;
        bf16x8 a[4];
#pragma unroll
        for (int kt = 0; kt < 4; ++kt) a[kt] = *(const bf16x8*)(qrow + kt * 32 + lk8);
        f32x4 acc[3] = {};
#pragma unroll
        for (int kt = 0; kt < 4; ++kt)
#pragma unroll
            for (int ut = 0; ut < 3; ++ut)
                acc[ut] = __builtin_amdgcn_mfma_f32_16x16x32_bf16(a[kt], bh[ut][kt], acc[ut], 0, 0, 0);
        __syncthreads();
#pragma unroll
        for (int ut = 0; ut < 3; ++ut)
#pragma unroll
            for (int r = 0; r < 4; ++r)
                sm[w][(l >> 4) * 4 + r][ut * 16 + lr] = acc[ut][r];
        __syncthreads();
        int part = l >> 4;
        float vb[12];
        float mx = -1e30f;
#pragma unroll
        for (int j = 0; j < 12; ++j) { vb[j] = sm[w][lr][part * 12 + j]; mx = fmaxf(mx, vb[j]); }
        mx = fmaxf(mx, __shfl_xor(mx, 16, 64));
        mx = fmaxf(mx, __shfl_xor(mx, 32, 64));
        float ssum = 0.f;
#pragma unroll
        for (int j = 0; j < 12; ++j) { vb[j] = __expf(vb[j] - mx); ssum += vb[j]; }
        ssum += __shfl_xor(ssum, 16, 64);
        ssum += __shfl_xor(ssum, 32, 64);
        float inv = 1.0f / ssum;
        unsigned short* dst = phbase + (size_t)(w * 128 + mt * 16 + lr) * 48 + part * 12;
#pragma unroll
        for (int j = 0; j < 12; ++j) dst[j] = f2b(vb[j] * inv);
    }
}

// ---------------- K2b: pw softmax over v (mt split over z) ----------------
__global__ __launch_bounds__(256) void k_pw(const unsigned short* __restrict__ Qx,
                                            const float* __restrict__ rel_w,
                                            unsigned short* __restrict__ PW) {
    __shared__ float sm[4][16][68];
    int y = blockIdx.x, f = blockIdx.y, mtz = blockIdx.z;
    int tid = threadIdx.x, l = tid & 63, w = tid >> 6;
    int lr = l & 15, lk8 = (l >> 4) * 8;
    bf16x8 bw[4][4];
#pragma unroll
    for (int vt = 0; vt < 4; ++vt) {
        int v = vt * 16 + lr, rr = y - v + 99;
#pragma unroll
        for (int kt = 0; kt < 4; ++kt) {
            const float* s = rel_w + rr * 128 + kt * 32 + lk8;
            float4 a0 = *(const float4*)s, a1 = *(const float4*)(s + 4);
            bf16x8 pk;
            pk[0] = (short)f2b(a0.x); pk[1] = (short)f2b(a0.y); pk[2] = (short)f2b(a0.z); pk[3] = (short)f2b(a0.w);
            pk[4] = (short)f2b(a1.x); pk[5] = (short)f2b(a1.y); pk[6] = (short)f2b(a1.z); pk[7] = (short)f2b(a1.w);
            bw[vt][kt] = pk;
        }
    }
    for (int mt = mtz * 2; mt < mtz * 2 + 2; ++mt) {
        int rg = w * 96 + mt * 16 + lr;
        int bn = rg / 48, xx = rg - bn * 48;
        const unsigned short* qrow = Qx + (size_t)((f * 48 + xx) * 512 + bn * 64 + y) * 128;
        bf16x8 a[4];
#pragma unroll
        for (int kt = 0; kt < 4; ++kt) a[kt] = *(const bf16x8*)(qrow + kt * 32 + lk8);
        f32x4 acc[4] = {};
#pragma unroll
        for (int kt = 0; kt < 4; ++kt)
#pragma unroll
            for (int vt = 0; vt < 4; ++vt)
                acc[vt] = __builtin_amdgcn_mfma_f32_16x16x32_bf16(a[kt], bw[vt][kt], acc[vt], 0, 0, 0);
        __syncthreads();
#pragma unroll
        for (int vt = 0; vt < 4; ++vt)
#pragma unroll
            for (int r = 0; r < 4; ++r)
                sm[w][(l >> 4) * 4 + r][vt * 16 + lr] = acc[vt][r];
        __syncthreads();
        int part = l >> 4;
        float vb[16];
        float mx = -1e30f;
#pragma unroll
        for (int j = 0; j < 16; ++j) { vb[j] = sm[w][lr][part * 16 + j]; mx = fmaxf(mx, vb[j]); }
        mx = fmaxf(mx, __shfl_xor(mx, 16, 64));
        mx = fmaxf(mx, __shfl_xor(mx, 32, 64));
        float ssum = 0.f;
#pragma unroll
        for (int j = 0; j < 16; ++j) { vb[j] = __expf(vb[j] - mx); ssum += vb[j]; }
        ssum += __shfl_xor(ssum, 16, 64);
        ssum += __shfl_xor(ssum, 32, 64);
        float inv = 1.0f / ssum;
        unsigned short* dst = PW + (size_t)((f * 64 + y) * 384 + rg) * 64 + part * 16;
#pragma unroll
        for (int j = 0; j < 16; ++j) dst[j] = f2b(vb[j] * inv);
    }
}

// ---------------- K3 (R9 structure): transposed MFMA, reg-stage + ds_write, 1 barrier/u ----------------
// Grid 768 = (24 q-tiles x 2 d-halves) x 16 fbn; 256 threads = 4 waves, each 16d x 128q.
// Per u: load u+1 -> regs (top), ds_read cur, 16 MFMA, ds_write u+1 -> other buf, barrier.
// Staging remap sd=tid>>3 (R10-proven conflict fix). 28.7 KB LDS, VGPR ~84 (no spill).
__global__ __launch_bounds__(256, 3) void k_attn(const unsigned short* __restrict__ PH,
                                                 const unsigned short* __restrict__ PW,
                                                 const unsigned short* __restrict__ Vt,
                                                 unsigned short* __restrict__ AO) {
    __shared__ unsigned short phl[48 * 128];       // [u][(q&15)*8 + (q>>4)] bf16 (12 KB)
    __shared__ unsigned short vbuf[2][64 * 64];    // [d][key-chunk swizzled] (2 x 8 KB)
    int bid = blockIdx.x;
    int r16 = bid & 15;
    int rest = bid >> 4;                            // 0..47
    int t = rest >> 1, dh = rest & 1;               // q-tile (128 rows), d-half
    int fbn = (r16 & 7) * 2 + (r16 >> 3);           // XCD-local V reuse
    int f = fbn >> 3, bidx = (fbn >> 2) & 1, nh = fbn & 3;
    int fb = f * 2 + bidx, bn = bidx * 4 + nh;
    int tid = threadIdx.x;
    int l = tid & 63, wd = tid >> 6;                // wave = 16-d slice
    int lr = l & 15, lg = l >> 4, lk8 = lg * 8;

    // V staging (remap): thread -> rows sd, sd+32; chunk sch (full 64-key row by 8 threads)
    const unsigned short* vsrc = Vt + (size_t)((fb * 4 + nh) * 128 + dh * 64) * HWSZ;
    int sd = tid >> 3, sch = tid & 7;               // sd 0..31, sch 0..7
    const unsigned short* vsrow0 = vsrc + (size_t)sd * HWSZ + sch * 8;
    const unsigned short* vsrow1 = vsrc + (size_t)(sd + 32) * HWSZ + sch * 8;
    int wo0 = sd * 64 + ((sch ^ (sd & 7)) * 8);
    int wo1 = (sd + 32) * 64 + ((sch ^ (sd & 7)) * 8);

    bf16x8 r0a = *(const bf16x8*)(vsrow0);
    bf16x8 r0b = *(const bf16x8*)(vsrow1);

    // stage ph: packed layout [u][(q&15)*8 + (q>>4)]
    for (int i = tid; i < 3072; i += 256) {
        int up2 = i >> 7, q = i & 127;
        int xy = t * 128 + q, x = xy >> 6, y = xy & 63;
        unsigned int wv = *(const unsigned int*)(PH + ((size_t)(f * 48 + x) * 512 + bn * 64 + y) * 48 + up2 * 2);
        int qoff = (q & 15) * 8 + (q >> 4);
        phl[(up2 * 2) * 128 + qoff]     = (unsigned short)(wv & 0xffffu);
        phl[(up2 * 2 + 1) * 128 + qoff] = (unsigned short)(wv >> 16);
    }
    // pw B-fragments: 8 n-frags x 2 k-halves in registers (loaded once)
    bf16x8 b[8][2];
#pragma unroll
    for (int n = 0; n < 8; ++n) {
        int xy = t * 128 + n * 16 + lr;
        int x = xy >> 6, y = xy & 63;
        const unsigned short* pwr = PW + ((size_t)(f * 64 + y) * 384 + bn * 48 + x) * 64;
        b[n][0] = *(const bf16x8*)(pwr + lk8);
        b[n][1] = *(const bf16x8*)(pwr + 32 + lk8);
    }
    *(bf16x8*)&vbuf[0][wo0] = r0a;
    *(bf16x8*)&vbuf[0][wo1] = r0b;
    __syncthreads();

    int arow = wd * 16 + lr;
    int ao0 = arow * 64 + ((lg ^ (arow & 7)) * 8);
    int ao1 = arow * 64 + (((4 + lg) ^ (arow & 7)) * 8);
    const unsigned short* phrow = &phl[lr * 8];
    f32x4 acc[8] = {};
    const f32x4 zero4 = {0.f, 0.f, 0.f, 0.f};
    int cur = 0;
    for (int u = 0; u < 48; ++u) {
        bf16x8 ra, rb;
        if (u < 47) {
            ra = *(const bf16x8*)(vsrow0 + (size_t)(u + 1) * 64);   // issue early
            rb = *(const bf16x8*)(vsrow1 + (size_t)(u + 1) * 64);
        }
        bf16x8 av0 = *(const bf16x8*)&vbuf[cur][ao0];
        bf16x8 av1 = *(const bf16x8*)&vbuf[cur][ao1];
        bf16x8 phv = *(const bf16x8*)(phrow + u * 128);             // 8 ph scalars for lane's q
#pragma unroll
        for (int n = 0; n < 8; ++n) {
            f32x4 Y = __builtin_amdgcn_mfma_f32_16x16x32_bf16(av0, b[n][0], zero4, 0, 0, 0);
            Y = __builtin_amdgcn_mfma_f32_16x16x32_bf16(av1, b[n][1], Y, 0, 0, 0);
            float p = b2f((unsigned short)phv[n]);
            acc[n] += p * Y;
        }
        if (u < 47) {
            *(bf16x8*)&vbuf[cur ^ 1][wo0] = ra;                      // write late
            *(bf16x8*)&vbuf[cur ^ 1][wo1] = rb;
        }
        __syncthreads();
        cur ^= 1;
    }
    // store: lane col q = t*128 + n*16 + lr; rows d = dh*64 + wd*16 + lg*4 (+r)
    unsigned short* aobase = AO + (size_t)fb * HWSZ * 512 + nh * 128 + dh * 64 + wd * 16 + lg * 4;
#pragma unroll
    for (int n = 0; n < 8; ++n) {
        int q = t * 128 + n * 16 + lr;
        uint2 val;
        val.x = (unsigned int)f2b(acc[n][0]) | ((unsigned int)f2b(acc[n][1]) << 16);
        val.y = (unsigned int)f2b(acc[n][2]) | ((unsigned int)f2b(acc[n][3]) << 16);
        *(uint2*)(aobase + (size_t)q * 512) = val;
    }
}

// ---------------- K4: out = fmap + gamma * (AO @ Wp^T), 32-row tiles (384 blocks) ----------------
__global__ __launch_bounds__(256) void k_proj(const unsigned short* __restrict__ AO,
                                              const unsigned short* __restrict__ Wpb,
                                              const float* __restrict__ f0,
                                              const float* __restrict__ f1,
                                              const float* __restrict__ gamma,
                                              float* __restrict__ out) {
    __shared__ unsigned short Asub[32 * 136];
    __shared__ unsigned short Bsub[128 * 136];
    int t = blockIdx.x, fb = blockIdx.y;
    int f = fb >> 1, bb = fb & 1;
    int tid = threadIdx.x;
    int l = tid & 63, w = tid >> 6;
    int wm = w >> 1, wn = w & 1;
    int lr = l & 15, lk8 = (l >> 4) * 8;
    f32x4 acc[4] = {};
    for (int ks = 0; ks < 4; ++ks) {
        if (ks) __syncthreads();
        for (int ch = tid; ch < 512; ch += 256) {
            int row = ch >> 4, seg = ch & 15;
            *(bf16x8*)&Asub[row * 136 + seg * 8] =
                *(const bf16x8*)(AO + (size_t)(fb * HWSZ + t * 32 + row) * 512 + ks * 128 + seg * 8);
        }
        for (int ch = tid; ch < 2048; ch += 256) {
            int row = ch >> 4, seg = ch & 15;
            *(bf16x8*)&Bsub[row * 136 + seg * 8] =
                *(const bf16x8*)(Wpb + (size_t)row * 512 + ks * 128 + seg * 8);
        }
        __syncthreads();
#pragma unroll
        for (int kt = 0; kt < 4; ++kt) {
            bf16x8 a, b[4];
            a = *(const bf16x8*)&Asub[(wm * 16 + lr) * 136 + kt * 32 + lk8];
#pragma unroll
            for (int n = 0; n < 4; ++n)
                b[n] = *(const bf16x8*)&Bsub[(wn * 64 + n * 16 + lr) * 136 + kt * 32 + lk8];
#pragma unroll
            for (int n = 0; n < 4; ++n)
                acc[n] = __builtin_amdgcn_mfma_f32_16x16x32_bf16(a, b[n], acc[n], 0, 0, 0);
        }
    }
    const float* fmapf = f ? f1 : f0;
    float g = gamma[0];
#pragma unroll
    for (int n = 0; n < 4; ++n) {
        int c = wn * 64 + n * 16 + lr;
        int pos0 = t * 32 + wm * 16 + (l >> 4) * 4;
        size_t addr = (size_t)(bb * 128 + c) * HWSZ + pos0;
        float4 fv = *(const float4*)(fmapf + addr);
        float4 ov;
        ov.x = fv.x + g * acc[n][0];
        ov.y = fv.y + g * acc[n][1];
        ov.z = fv.z + g * acc[n][2];
        ov.w = fv.w + g * acc[n][3];
        *(float4*)(out + (size_t)f * 786432 + addr) = ov;
    }
}

extern "C" void kernel_launch(void* const* d_in, const int* in_sizes, int n_in,
                              void* d_out, int out_size, void* d_ws, size_t ws_size,
                              hipStream_t stream) {
    (void)in_sizes; (void)n_in; (void)out_size; (void)ws_size;
    const float* fmap1 = (const float*)d_in[0];
    const float* fmap2 = (const float*)d_in[1];
    const float* Wqk   = (const float*)d_in[2];
    const float* Wv    = (const float*)d_in[3];
    const float* rel_h = (const float*)d_in[4];
    const float* rel_w = (const float*)d_in[5];
    const float* Wp    = (const float*)d_in[6];
    const float* gamma = (const float*)d_in[7];
    float* out = (float*)d_out;
    char* ws = (char*)d_ws;

    unsigned short* Xb   = (unsigned short*)(ws + 0);
    unsigned short* Wcat = (unsigned short*)(ws + 3145728);
    unsigned short* Wpb  = (unsigned short*)(ws + 3407872);
    unsigned short* Qx   = (unsigned short*)(ws + 3538944);
    unsigned short* AO   = Qx;                               // alias: Qx dead after k_ph/k_pw
    unsigned short* Vt   = (unsigned short*)(ws + 16121856);
    unsigned short* PH   = (unsigned short*)(ws + 28704768);
    unsigned short* PW   = (unsigned short*)(ws + 33423360);

    k_transpose<<<dim3(96, 4, 4), dim3(32, 8), 0, stream>>>(fmap1, fmap2, Xb);
    k_weights<<<dim3(768), dim3(256), 0, stream>>>(Wqk, Wv, Wp, Wcat, Wpb);
    k_qv<<<dim3(48, 8, 4), dim3(256), 0, stream>>>(Xb, Wcat, Qx, Vt);
    k_ph<<<dim3(48, 2, 4), dim3(256), 0, stream>>>(Qx, rel_h, PH);
    k_pw<<<dim3(64, 2, 3), dim3(256), 0, stream>>>(Qx, rel_w, PW);
    k_attn<<<dim3(768), dim3(256), 0, stream>>>(PH, PW, Vt, AO);
    k_proj<<<dim3(96, 4), dim3(256), 0, stream>>>(AO, Wpb, fmap1, fmap2, gamma, out);
}

// Round 21
// 102.863 us; speedup vs baseline: 6.7395x; 1.0824x over previous
//
#include <hip/hip_runtime.h>
#include <cstdint>
#include <cstddef>

typedef short bf16x8 __attribute__((ext_vector_type(8)));
typedef float f32x4 __attribute__((ext_vector_type(4)));

#define HH 48
#define WW 64
#define HWSZ 3072
#define SCALE_Q 0.08838834764831845f

__device__ __forceinline__ float b2f(unsigned short u) {
    union { unsigned int i; float f; } c; c.i = ((unsigned int)u) << 16; return c.f;
}
__device__ __forceinline__ unsigned short f2b(float f) {
    union { float f; unsigned int i; } c; c.f = f;
    unsigned int r = (c.i + 0x7fffu + ((c.i >> 16) & 1u)) >> 16;
    return (unsigned short)r;
}

// ---------------- K0: fused prep — transpose fmap + convert weights ----------------
__global__ __launch_bounds__(256) void k_prep(const float* __restrict__ f0,
                                              const float* __restrict__ f1,
                                              const float* __restrict__ Wqk,
                                              const float* __restrict__ Wv,
                                              const float* __restrict__ Wp,
                                              unsigned short* __restrict__ Xb,
                                              unsigned short* __restrict__ Wcat,
                                              unsigned short* __restrict__ Wpb) {
    int bid = blockIdx.x;
    int tid = threadIdx.x;
    if (bid < 1536) {
        __shared__ float t[32][33];
        int px = bid % 96, rest = bid / 96;
        int cy = rest & 3, fb = rest >> 2;
        int f = fb >> 1, bb = fb & 1;
        const float* src = f ? f1 : f0;
        int pT = px * 32, cT = cy * 32;
        int tx = tid & 31, ty = tid >> 5;
#pragma unroll
        for (int i = 0; i < 4; ++i) {
            int c = cT + ty + i * 8, pos = pT + tx;
            t[ty + i * 8][tx] = src[(size_t)(bb * 128 + c) * HWSZ + pos];
        }
        __syncthreads();
#pragma unroll
        for (int i = 0; i < 4; ++i) {
            int pos = pT + ty + i * 8, c = cT + tx;
            Xb[(size_t)(fb * HWSZ + pos) * 128 + c] = f2b(t[tx][ty + i * 8]);
        }
    } else {
        int idx = (bid - 1536) * 256 + tid;
        if (idx < 131072) {
            int o = idx >> 7, c = idx & 127;
            float v = (o < 512) ? Wqk[o * 128 + c] * SCALE_Q : Wv[(o - 512) * 128 + c];
            Wcat[idx] = f2b(v);
        } else {
            int j = idx - 131072;
            Wpb[j] = f2b(Wp[j]);
        }
    }
}

// ---------------- K1: q/v projections; V stored as [fbn][d][key] ----------------
__global__ __launch_bounds__(256) void k_qv(const unsigned short* __restrict__ Xb,
                                            const unsigned short* __restrict__ Wcat,
                                            unsigned short* __restrict__ Qx,
                                            unsigned short* __restrict__ Vt) {
    __shared__ unsigned short Asub[64 * 136];
    __shared__ unsigned short Bsub[128 * 136];
    int mt = blockIdx.x, nt = blockIdx.y, fb = blockIdx.z;
    int tid = threadIdx.x;
    const unsigned short* asrc = Xb + (size_t)(fb * HWSZ + mt * 64) * 128;
    const unsigned short* bsrc = Wcat + (size_t)nt * 128 * 128;
    for (int ch = tid; ch < 1024; ch += 256) {
        int row = ch >> 4, seg = ch & 15;
        *(bf16x8*)&Asub[row * 136 + seg * 8] = *(const bf16x8*)(asrc + ch * 8);
    }
    for (int ch = tid; ch < 2048; ch += 256) {
        int row = ch >> 4, seg = ch & 15;
        *(bf16x8*)&Bsub[row * 136 + seg * 8] = *(const bf16x8*)(bsrc + ch * 8);
    }
    __syncthreads();
    int l = tid & 63, w = tid >> 6;
    int wm = w >> 1, wn = w & 1;
    int lr = l & 15, lk8 = (l >> 4) * 8;
    f32x4 acc[2][4] = {};
#pragma unroll
    for (int kt = 0; kt < 4; ++kt) {
        bf16x8 a[2], b[4];
#pragma unroll
        for (int m = 0; m < 2; ++m)
            a[m] = *(const bf16x8*)&Asub[(wm * 32 + m * 16 + lr) * 136 + kt * 32 + lk8];
#pragma unroll
        for (int n = 0; n < 4; ++n)
            b[n] = *(const bf16x8*)&Bsub[(wn * 64 + n * 16 + lr) * 136 + kt * 32 + lk8];
#pragma unroll
        for (int m = 0; m < 2; ++m)
#pragma unroll
            for (int n = 0; n < 4; ++n)
                acc[m][n] = __builtin_amdgcn_mfma_f32_16x16x32_bf16(a[m], b[n], acc[m][n], 0, 0, 0);
    }
    int f = fb >> 1, bb = fb & 1;
#pragma unroll
    for (int m = 0; m < 2; ++m)
#pragma unroll
        for (int n = 0; n < 4; ++n) {
            int o = nt * 128 + wn * 64 + n * 16 + lr;
            int pos0 = mt * 64 + wm * 32 + m * 16 + (l >> 4) * 4;
            if (o < 512) {
                int nh = o >> 7, d = o & 127;
#pragma unroll
                for (int r = 0; r < 4; ++r) {
                    int pos = pos0 + r, x = pos >> 6, y = pos & 63;
                    Qx[(size_t)((f * 48 + x) * 512 + (bb * 4 + nh) * 64 + y) * 128 + d] = f2b(acc[m][n][r]);
                }
            } else {
                int oo = o - 512, nh = oo >> 7, d = oo & 127;
                uint2 val;
                val.x = (unsigned int)f2b(acc[m][n][0]) | ((unsigned int)f2b(acc[m][n][1]) << 16);
                val.y = (unsigned int)f2b(acc[m][n][2]) | ((unsigned int)f2b(acc[m][n][3]) << 16);
                *(uint2*)&Vt[(size_t)((fb * 4 + nh) * 128 + d) * HWSZ + pos0] = val;
            }
        }
}

// ---------------- K2: merged softmax kernel (ph role: bid<384, pw role: bid>=384) ----------------
__global__ __launch_bounds__(256) void k_sm(const unsigned short* __restrict__ Qx,
                                            const float* __restrict__ rel_h,
                                            const float* __restrict__ rel_w,
                                            unsigned short* __restrict__ PH,
                                            unsigned short* __restrict__ PW) {
    __shared__ float sm[4][16][68];
    int bid = blockIdx.x;
    int tid = threadIdx.x, l = tid & 63, w = tid >> 6;
    int lr = l & 15, lk8 = (l >> 4) * 8;
    if (bid < 384) {
        // ---- ph: softmax over u (48) ----
        int x = bid % 48, f = (bid / 48) & 1, mtz = bid / 96;
        bf16x8 bh[3][4];
#pragma unroll
        for (int ut = 0; ut < 3; ++ut) {
            int u = ut * 16 + lr, rr = x - u + 99;
#pragma unroll
            for (int kt = 0; kt < 4; ++kt) {
                const float* s = rel_h + rr * 128 + kt * 32 + lk8;
                float4 a0 = *(const float4*)s, a1 = *(const float4*)(s + 4);
                bf16x8 pk;
                pk[0] = (short)f2b(a0.x); pk[1] = (short)f2b(a0.y); pk[2] = (short)f2b(a0.z); pk[3] = (short)f2b(a0.w);
                pk[4] = (short)f2b(a1.x); pk[5] = (short)f2b(a1.y); pk[6] = (short)f2b(a1.z); pk[7] = (short)f2b(a1.w);
                bh[ut][kt] = pk;
            }
        }
        const unsigned short* qbase = Qx + (size_t)(f * 48 + x) * 512 * 128;
        unsigned short* phbase = PH + (size_t)(f * 48 + x) * 512 * 48;
        for (int mt = mtz * 2; mt < mtz * 2 + 2; ++mt) {
            int rg = w * 128 + mt * 16 + lr;
            const unsigned short* qrow = qbase + (size_t)rg * 128;
            bf16x8 a[4];
#pragma unroll
            for (int kt = 0; kt < 4; ++kt) a[kt] = *(const bf16x8*)(qrow + kt * 32 + lk8);
            f32x4 acc[3] = {};
#pragma unroll
            for (int kt = 0; kt < 4; ++kt)
#pragma unroll
                for (int ut = 0; ut < 3; ++ut)
                    acc[ut] = __builtin_amdgcn_mfma_f32_16x16x32_bf16(a[kt], bh[ut][kt], acc[ut], 0, 0, 0);
            __syncthreads();
#pragma unroll
            for (int ut = 0; ut < 3; ++ut)
#pragma unroll
                for (int r = 0; r < 4; ++r)
                    sm[w][(l >> 4) * 4 + r][ut * 16 + lr] = acc[ut][r];
            __syncthreads();
            int part = l >> 4;
            float vb[12];
            float mx = -1e30f;
#pragma unroll
            for (int j = 0; j < 12; ++j) { vb[j] = sm[w][lr][part * 12 + j]; mx = fmaxf(mx, vb[j]); }
            mx = fmaxf(mx, __shfl_xor(mx, 16, 64));
            mx = fmaxf(mx, __shfl_xor(mx, 32, 64));
            float ssum = 0.f;
#pragma unroll
            for (int j = 0; j < 12; ++j) { vb[j] = __expf(vb[j] - mx); ssum += vb[j]; }
            ssum += __shfl_xor(ssum, 16, 64);
            ssum += __shfl_xor(ssum, 32, 64);
            float inv = 1.0f / ssum;
            unsigned short* dst = phbase + (size_t)(w * 128 + mt * 16 + lr) * 48 + part * 12;
#pragma unroll
            for (int j = 0; j < 12; ++j) dst[j] = f2b(vb[j] * inv);
        }
    } else {
        // ---- pw: softmax over v (64) ----
        int b2 = bid - 384;
        int y = b2 % 64, f = (b2 / 64) & 1, mtz = b2 / 128;
        bf16x8 bw[4][4];
#pragma unroll
        for (int vt = 0; vt < 4; ++vt) {
            int v = vt * 16 + lr, rr = y - v + 99;
#pragma unroll
            for (int kt = 0; kt < 4; ++kt) {
                const float* s = rel_w + rr * 128 + kt * 32 + lk8;
                float4 a0 = *(const float4*)s, a1 = *(const float4*)(s + 4);
                bf16x8 pk;
                pk[0] = (short)f2b(a0.x); pk[1] = (short)f2b(a0.y); pk[2] = (short)f2b(a0.z); pk[3] = (short)f2b(a0.w);
                pk[4] = (short)f2b(a1.x); pk[5] = (short)f2b(a1.y); pk[6] = (short)f2b(a1.z); pk[7] = (short)f2b(a1.w);
                bw[vt][kt] = pk;
            }
        }
        for (int mt = mtz * 2; mt < mtz * 2 + 2; ++mt) {
            int rg = w * 96 + mt * 16 + lr;
            int bn = rg / 48, xx = rg - bn * 48;
            const unsigned short* qrow = Qx + (size_t)((f * 48 + xx) * 512 + bn * 64 + y) * 128;
            bf16x8 a[4];
#pragma unroll
            for (int kt = 0; kt < 4; ++kt) a[kt] = *(const bf16x8*)(qrow + kt * 32 + lk8);
            f32x4 acc[4] = {};
#pragma unroll
            for (int kt = 0; kt < 4; ++kt)
#pragma unroll
                for (int vt = 0; vt < 4; ++vt)
                    acc[vt] = __builtin_amdgcn_mfma_f32_16x16x32_bf16(a[kt], bw[vt][kt], acc[vt], 0, 0, 0);
            __syncthreads();
#pragma unroll
            for (int vt = 0; vt < 4; ++vt)
#pragma unroll
                for (int r = 0; r < 4; ++r)
                    sm[w][(l >> 4) * 4 + r][vt * 16 + lr] = acc[vt][r];
            __syncthreads();
            int part = l >> 4;
            float vb[16];
            float mx = -1e30f;
#pragma unroll
            for (int j = 0; j < 16; ++j) { vb[j] = sm[w][lr][part * 16 + j]; mx = fmaxf(mx, vb[j]); }
            mx = fmaxf(mx, __shfl_xor(mx, 16, 64));
            mx = fmaxf(mx, __shfl_xor(mx, 32, 64));
            float ssum = 0.f;
#pragma unroll
            for (int j = 0; j < 16; ++j) { vb[j] = __expf(vb[j] - mx); ssum += vb[j]; }
            ssum += __shfl_xor(ssum, 16, 64);
            ssum += __shfl_xor(ssum, 32, 64);
            float inv = 1.0f / ssum;
            unsigned short* dst = PW + (size_t)((f * 64 + y) * 384 + rg) * 64 + part * 16;
#pragma unroll
            for (int j = 0; j < 16; ++j) dst[j] = f2b(vb[j] * inv);
        }
    }
}

// ---------------- K3 (R20/R9 structure): transposed MFMA, reg-stage + ds_write, 1 barrier/u ----------------
__global__ __launch_bounds__(256, 3) void k_attn(const unsigned short* __restrict__ PH,
                                                 const unsigned short* __restrict__ PW,
                                                 const unsigned short* __restrict__ Vt,
                                                 unsigned short* __restrict__ AO) {
    __shared__ unsigned short phl[48 * 128];       // [u][(q&15)*8 + (q>>4)] bf16 (12 KB)
    __shared__ unsigned short vbuf[2][64 * 64];    // [d][key-chunk swizzled] (2 x 8 KB)
    int bid = blockIdx.x;
    int r16 = bid & 15;
    int rest = bid >> 4;                            // 0..47
    int t = rest >> 1, dh = rest & 1;               // q-tile (128 rows), d-half
    int fbn = (r16 & 7) * 2 + (r16 >> 3);           // XCD-local V reuse
    int f = fbn >> 3, bidx = (fbn >> 2) & 1, nh = fbn & 3;
    int fb = f * 2 + bidx, bn = bidx * 4 + nh;
    int tid = threadIdx.x;
    int l = tid & 63, wd = tid >> 6;                // wave = 16-d slice
    int lr = l & 15, lg = l >> 4, lk8 = lg * 8;

    // V staging (remap): thread -> rows sd, sd+32; chunk sch
    const unsigned short* vsrc = Vt + (size_t)((fb * 4 + nh) * 128 + dh * 64) * HWSZ;
    int sd = tid >> 3, sch = tid & 7;
    const unsigned short* vsrow0 = vsrc + (size_t)sd * HWSZ + sch * 8;
    const unsigned short* vsrow1 = vsrc + (size_t)(sd + 32) * HWSZ + sch * 8;
    int wo0 = sd * 64 + ((sch ^ (sd & 7)) * 8);
    int wo1 = (sd + 32) * 64 + ((sch ^ (sd & 7)) * 8);

    bf16x8 r0a = *(const bf16x8*)(vsrow0);
    bf16x8 r0b = *(const bf16x8*)(vsrow1);

    // stage ph: packed layout [u][(q&15)*8 + (q>>4)]
    for (int i = tid; i < 3072; i += 256) {
        int up2 = i >> 7, q = i & 127;
        int xy = t * 128 + q, x = xy >> 6, y = xy & 63;
        unsigned int wv = *(const unsigned int*)(PH + ((size_t)(f * 48 + x) * 512 + bn * 64 + y) * 48 + up2 * 2);
        int qoff = (q & 15) * 8 + (q >> 4);
        phl[(up2 * 2) * 128 + qoff]     = (unsigned short)(wv & 0xffffu);
        phl[(up2 * 2 + 1) * 128 + qoff] = (unsigned short)(wv >> 16);
    }
    // pw B-fragments: 8 n-frags x 2 k-halves in registers (loaded once)
    bf16x8 b[8][2];
#pragma unroll
    for (int n = 0; n < 8; ++n) {
        int xy = t * 128 + n * 16 + lr;
        int x = xy >> 6, y = xy & 63;
        const unsigned short* pwr = PW + ((size_t)(f * 64 + y) * 384 + bn * 48 + x) * 64;
        b[n][0] = *(const bf16x8*)(pwr + lk8);
        b[n][1] = *(const bf16x8*)(pwr + 32 + lk8);
    }
    *(bf16x8*)&vbuf[0][wo0] = r0a;
    *(bf16x8*)&vbuf[0][wo1] = r0b;
    __syncthreads();

    int arow = wd * 16 + lr;
    int ao0 = arow * 64 + ((lg ^ (arow & 7)) * 8);
    int ao1 = arow * 64 + (((4 + lg) ^ (arow & 7)) * 8);
    const unsigned short* phrow = &phl[lr * 8];
    f32x4 acc[8] = {};
    const f32x4 zero4 = {0.f, 0.f, 0.f, 0.f};
    int cur = 0;
    for (int u = 0; u < 48; ++u) {
        bf16x8 ra, rb;
        if (u < 47) {
            ra = *(const bf16x8*)(vsrow0 + (size_t)(u + 1) * 64);   // issue early
            rb = *(const bf16x8*)(vsrow1 + (size_t)(u + 1) * 64);
        }
        bf16x8 av0 = *(const bf16x8*)&vbuf[cur][ao0];
        bf16x8 av1 = *(const bf16x8*)&vbuf[cur][ao1];
        bf16x8 phv = *(const bf16x8*)(phrow + u * 128);
#pragma unroll
        for (int n = 0; n < 8; ++n) {
            f32x4 Y = __builtin_amdgcn_mfma_f32_16x16x32_bf16(av0, b[n][0], zero4, 0, 0, 0);
            Y = __builtin_amdgcn_mfma_f32_16x16x32_bf16(av1, b[n][1], Y, 0, 0, 0);
            float p = b2f((unsigned short)phv[n]);
            acc[n] += p * Y;
        }
        if (u < 47) {
            *(bf16x8*)&vbuf[cur ^ 1][wo0] = ra;                      // write late
            *(bf16x8*)&vbuf[cur ^ 1][wo1] = rb;
        }
        __syncthreads();
        cur ^= 1;
    }
    // store: lane col q = t*128 + n*16 + lr; rows d = dh*64 + wd*16 + lg*4 (+r)
    unsigned short* aobase = AO + (size_t)fb * HWSZ * 512 + nh * 128 + dh * 64 + wd * 16 + lg * 4;
#pragma unroll
    for (int n = 0; n < 8; ++n) {
        int q = t * 128 + n * 16 + lr;
        uint2 val;
        val.x = (unsigned int)f2b(acc[n][0]) | ((unsigned int)f2b(acc[n][1]) << 16);
        val.y = (unsigned int)f2b(acc[n][2]) | ((unsigned int)f2b(acc[n][3]) << 16);
        *(uint2*)(aobase + (size_t)q * 512) = val;
    }
}

// ---------------- K4: out = fmap + gamma * (AO @ Wp^T), 32-row tiles (384 blocks) ----------------
__global__ __launch_bounds__(256) void k_proj(const unsigned short* __restrict__ AO,
                                              const unsigned short* __restrict__ Wpb,
                                              const float* __restrict__ f0,
                                              const float* __restrict__ f1,
                                              const float* __restrict__ gamma,
                                              float* __restrict__ out) {
    __shared__ unsigned short Asub[32 * 136];
    __shared__ unsigned short Bsub[128 * 136];
    int t = blockIdx.x, fb = blockIdx.y;
    int f = fb >> 1, bb = fb & 1;
    int tid = threadIdx.x;
    int l = tid & 63, w = tid >> 6;
    int wm = w >> 1, wn = w & 1;
    int lr = l & 15, lk8 = (l >> 4) * 8;
    f32x4 acc[4] = {};
    for (int ks = 0; ks < 4; ++ks) {
        if (ks) __syncthreads();
        for (int ch = tid; ch < 512; ch += 256) {
            int row = ch >> 4, seg = ch & 15;
            *(bf16x8*)&Asub[row * 136 + seg * 8] =
                *(const bf16x8*)(AO + (size_t)(fb * HWSZ + t * 32 + row) * 512 + ks * 128 + seg * 8);
        }
        for (int ch = tid; ch < 2048; ch += 256) {
            int row = ch >> 4, seg = ch & 15;
            *(bf16x8*)&Bsub[row * 136 + seg * 8] =
                *(const bf16x8*)(Wpb + (size_t)row * 512 + ks * 128 + seg * 8);
        }
        __syncthreads();
#pragma unroll
        for (int kt = 0; kt < 4; ++kt) {
            bf16x8 a, b[4];
            a = *(const bf16x8*)&Asub[(wm * 16 + lr) * 136 + kt * 32 + lk8];
#pragma unroll
            for (int n = 0; n < 4; ++n)
                b[n] = *(const bf16x8*)&Bsub[(wn * 64 + n * 16 + lr) * 136 + kt * 32 + lk8];
#pragma unroll
            for (int n = 0; n < 4; ++n)
                acc[n] = __builtin_amdgcn_mfma_f32_16x16x32_bf16(a, b[n], acc[n], 0, 0, 0);
        }
    }
    const float* fmapf = f ? f1 : f0;
    float g = gamma[0];
#pragma unroll
    for (int n = 0; n < 4; ++n) {
        int c = wn * 64 + n * 16 + lr;
        int pos0 = t * 32 + wm * 16 + (l >> 4) * 4;
        size_t addr = (size_t)(bb * 128 + c) * HWSZ + pos0;
        float4 fv = *(const float4*)(fmapf + addr);
        float4 ov;
        ov.x = fv.x + g * acc[n][0];
        ov.y = fv.y + g * acc[n][1];
        ov.z = fv.z + g * acc[n][2];
        ov.w = fv.w + g * acc[n][3];
        *(float4*)(out + (size_t)f * 786432 + addr) = ov;
    }
}

extern "C" void kernel_launch(void* const* d_in, const int* in_sizes, int n_in,
                              void* d_out, int out_size, void* d_ws, size_t ws_size,
                              hipStream_t stream) {
    (void)in_sizes; (void)n_in; (void)out_size; (void)ws_size;
    const float* fmap1 = (const float*)d_in[0];
    const float* fmap2 = (const float*)d_in[1];
    const float* Wqk   = (const float*)d_in[2];
    const float* Wv    = (const float*)d_in[3];
    const float* rel_h = (const float*)d_in[4];
    const float* rel_w = (const float*)d_in[5];
    const float* Wp    = (const float*)d_in[6];
    const float* gamma = (const float*)d_in[7];
    float* out = (float*)d_out;
    char* ws = (char*)d_ws;

    unsigned short* Xb   = (unsigned short*)(ws + 0);
    unsigned short* Wcat = (unsigned short*)(ws + 3145728);
    unsigned short* Wpb  = (unsigned short*)(ws + 3407872);
    unsigned short* Qx   = (unsigned short*)(ws + 3538944);
    unsigned short* AO   = Qx;                               // alias: Qx dead after k_sm
    unsigned short* Vt   = (unsigned short*)(ws + 16121856);
    unsigned short* PH   = (unsigned short*)(ws + 28704768);
    unsigned short* PW   = (unsigned short*)(ws + 33423360);

    k_prep<<<dim3(2304), dim3(256), 0, stream>>>(fmap1, fmap2, Wqk, Wv, Wp, Xb, Wcat, Wpb);
    k_qv<<<dim3(48, 8, 4), dim3(256), 0, stream>>>(Xb, Wcat, Qx, Vt);
    k_sm<<<dim3(768), dim3(256), 0, stream>>>(Qx, rel_h, rel_w, PH, PW);
    k_attn<<<dim3(768), dim3(256), 0, stream>>>(PH, PW, Vt, AO);
    k_proj<<<dim3(96, 4), dim3(256), 0, stream>>>(AO, Wpb, fmap1, fmap2, gamma, out);
}